// Round 1
// baseline (246.711 us; speedup 1.0000x reference)
//
#include <hip/hip_runtime.h>

// SpatialBorderLoss: single-scalar reduction over 1e6 rows.
// ws layout: [0] double sum_dist_out, [8] uint cnt_out, [12] uint wpos
// Memory-bound: 108 MB read -> ~17us floor at 6.3 TB/s.

__global__ void sbl_init_ws(double* g_sum, unsigned int* g_cnt, unsigned int* g_wpos) {
    *g_sum = 0.0;
    *g_cnt = 0u;
    *g_wpos = 0u;
}

__global__ void __launch_bounds__(256) sbl_main(
    const float* __restrict__ pts,      // [n,18]
    const float* __restrict__ quads,    // [n,8]
    const float* __restrict__ weight,   // [n]
    double* __restrict__ g_sum,
    unsigned int* __restrict__ g_cnt,
    unsigned int* __restrict__ g_wpos,
    int n)
{
    int tid = blockIdx.x * blockDim.x + threadIdx.x;
    int stride = gridDim.x * blockDim.x;

    float local_sum = 0.0f;
    unsigned int local_cnt = 0u;
    unsigned int local_wpos = 0u;

    for (int r = tid; r < n; r += stride) {
        // quad: 8 floats, base r*32 B -> 16B aligned, two float4 loads
        const float4* q4 = reinterpret_cast<const float4*>(quads + (size_t)r * 8);
        float4 qa = q4[0];
        float4 qb = q4[1];
        const float vx0 = qa.x, vy0 = qa.y, vx1 = qa.z, vy1 = qa.w;
        const float vx2 = qb.x, vy2 = qb.y, vx3 = qb.z, vy3 = qb.w;

        const float cx = (vx0 + vx2) * 0.5f;
        const float cy = (vy0 + vy2) * 0.5f;

        // pts row: 18 floats, base r*72 B -> 8B aligned, nine float2 loads
        const float2* p2 = reinterpret_cast<const float2*>(pts + (size_t)r * 18);

        #pragma unroll
        for (int k = 0; k < 9; ++k) {
            float2 p = p2[k];
            const float px = p.x, py = p.y;

            int crossings = 0;
            // edges (v_i, v_{i-1}) matching jnp.roll(v, 1): (0,3),(1,0),(2,1),(3,2)
            {
                bool str_ = (vy0 > py) != (vy3 > py);
                float xi = (vx3 - vx0) * (py - vy0) / (vy3 - vy0) + vx0;
                crossings += (str_ && (px < xi)) ? 1 : 0;
            }
            {
                bool str_ = (vy1 > py) != (vy0 > py);
                float xi = (vx0 - vx1) * (py - vy1) / (vy0 - vy1) + vx1;
                crossings += (str_ && (px < xi)) ? 1 : 0;
            }
            {
                bool str_ = (vy2 > py) != (vy1 > py);
                float xi = (vx1 - vx2) * (py - vy2) / (vy1 - vy2) + vx2;
                crossings += (str_ && (px < xi)) ? 1 : 0;
            }
            {
                bool str_ = (vy3 > py) != (vy2 > py);
                float xi = (vx2 - vx3) * (py - vy3) / (vy2 - vy3) + vx3;
                crossings += (str_ && (px < xi)) ? 1 : 0;
            }

            bool outside = ((crossings & 1) == 0);
            if (outside) {
                float dx = px - cx;
                float dy = py - cy;
                local_sum += 0.2f * sqrtf(dx * dx + dy * dy);
                local_cnt += 1u;
            }
        }

        local_wpos += (weight[r] > 0.0f) ? 1u : 0u;
    }

    // ---- wave (64-lane) reduction ----
    #pragma unroll
    for (int off = 32; off > 0; off >>= 1) {
        local_sum  += __shfl_down(local_sum, off, 64);
        local_cnt  += __shfl_down(local_cnt, off, 64);
        local_wpos += __shfl_down(local_wpos, off, 64);
    }

    // ---- block reduction across 4 waves ----
    __shared__ float  s_sum[4];
    __shared__ unsigned int s_cnt[4];
    __shared__ unsigned int s_wpos[4];
    int lane = threadIdx.x & 63;
    int wave = threadIdx.x >> 6;
    if (lane == 0) {
        s_sum[wave] = local_sum;
        s_cnt[wave] = local_cnt;
        s_wpos[wave] = local_wpos;
    }
    __syncthreads();
    if (threadIdx.x == 0) {
        double bsum = 0.0;
        unsigned int bcnt = 0u, bwpos = 0u;
        #pragma unroll
        for (int i = 0; i < 4; ++i) {
            bsum += (double)s_sum[i];
            bcnt += s_cnt[i];
            bwpos += s_wpos[i];
        }
        atomicAdd(g_sum, bsum);
        atomicAdd(g_cnt, bcnt);
        atomicAdd(g_wpos, bwpos);
    }
}

__global__ void sbl_finalize(const double* __restrict__ g_sum,
                             const unsigned int* __restrict__ g_cnt,
                             const unsigned int* __restrict__ g_wpos,
                             float* __restrict__ out)
{
    double s = *g_sum;
    unsigned int c = *g_cnt;
    unsigned int w = *g_wpos;
    double loss_sb = (c > 0u) ? (s / (double)(c < 1u ? 1u : c)) : 0.0;
    double avg_factor = (double)w + 1e-6;
    out[0] = (float)(loss_sb / avg_factor);
}

extern "C" void kernel_launch(void* const* d_in, const int* in_sizes, int n_in,
                              void* d_out, int out_size, void* d_ws, size_t ws_size,
                              hipStream_t stream) {
    const float* pts     = (const float*)d_in[0];   // [n,18]
    const float* quads   = (const float*)d_in[1];   // [n,8]
    const float* weight  = (const float*)d_in[2];   // [n]
    float* out = (float*)d_out;

    int n = in_sizes[2];  // rows

    double* g_sum = (double*)d_ws;
    unsigned int* g_cnt  = (unsigned int*)((char*)d_ws + 8);
    unsigned int* g_wpos = (unsigned int*)((char*)d_ws + 12);

    sbl_init_ws<<<1, 1, 0, stream>>>(g_sum, g_cnt, g_wpos);

    int block = 256;
    int grid = (n + block - 1) / block;
    sbl_main<<<grid, block, 0, stream>>>(pts, quads, weight, g_sum, g_cnt, g_wpos, n);

    sbl_finalize<<<1, 1, 0, stream>>>(g_sum, g_cnt, g_wpos, out);
}

// Round 2
// 142.547 us; speedup vs baseline: 1.7307x; 1.7307x over previous
//
#include <hip/hip_runtime.h>

// SpatialBorderLoss — per-POINT parallel version.
//
// Round-1 post-mortem: one-thread-per-row gave 72B-strided loads ->
// latency-bound at 379 GB/s (4.7% peak), VALUBusy 14.6%. Fix: thread = one of
// the 9*N points; float2 index for point p is exactly p -> fully coalesced.
// Divide removed via sign-adjusted multiply compare (straddle pins sign of d).
// Per-block partials in ws (no atomics, no init kernel); 1-wave finalize.
//
// ws layout: double part_sum[2048] @ 0       (16 KB)
//            uint   part_cnt[2048] @ 16384   ( 8 KB)
//            uint   part_wpos[2048]@ 24576   ( 8 KB)

#define SBL_NBLOCKS 2048
#define SBL_BLOCK   256

__global__ void __launch_bounds__(SBL_BLOCK) sbl_main(
    const float* __restrict__ pts,      // [n,18]
    const float* __restrict__ quads,    // [n,8]
    const float* __restrict__ weight,   // [n]
    double* __restrict__ part_sum,
    unsigned int* __restrict__ part_cnt,
    unsigned int* __restrict__ part_wpos,
    int n)
{
    const int gid    = blockIdx.x * SBL_BLOCK + threadIdx.x;
    const int stride = gridDim.x * SBL_BLOCK;
    const int total  = n * 9;

    const float2* __restrict__ p2 = reinterpret_cast<const float2*>(pts);
    const float4* __restrict__ q4 = reinterpret_cast<const float4*>(quads);

    float local_sum = 0.0f;
    unsigned int local_cnt = 0u;
    unsigned int local_wpos = 0u;

    for (int p = gid; p < total; p += stride) {
        const int row = (int)((unsigned int)p / 9u);

        const float2 pxy = p2[p];          // fully coalesced: index == p
        const float px = pxy.x, py = pxy.y;

        const float4 qa = q4[(size_t)row * 2];      // x1 y1 x2 y2
        const float4 qb = q4[(size_t)row * 2 + 1];  // x3 y3 x4 y4
        const float vx0 = qa.x, vy0 = qa.y, vx1 = qa.z, vy1 = qa.w;
        const float vx2 = qb.x, vy2 = qb.y, vx3 = qb.z, vy3 = qb.w;

        int crossings = 0;
        // Edge (v_i, v_{i-1}) per jnp.roll(v,1): (0,3),(1,0),(2,1),(3,2).
        // straddle guarantees d != 0 and fixes its sign, so
        // px < (vxj-vx)*(py-vy)/d + vx  <=>  sign-adjusted multiply compare.
        #define SBL_EDGE(VX, VY, VXJ, VYJ)                                   \
        do {                                                                 \
            bool str_ = ((VY) > py) != ((VYJ) > py);                         \
            float d   = (VYJ) - (VY);                                        \
            float num = ((VXJ) - (VX)) * (py - (VY));                        \
            float lhs = (px - (VX)) * d;                                     \
            bool cond = (d > 0.0f) ? (lhs < num) : (lhs > num);              \
            crossings += (str_ && cond) ? 1 : 0;                             \
        } while (0)

        SBL_EDGE(vx0, vy0, vx3, vy3);
        SBL_EDGE(vx1, vy1, vx0, vy0);
        SBL_EDGE(vx2, vy2, vx1, vy1);
        SBL_EDGE(vx3, vy3, vx2, vy2);
        #undef SBL_EDGE

        if ((crossings & 1) == 0) {        // outside
            const float cx = (vx0 + vx2) * 0.5f;
            const float cy = (vy0 + vy2) * 0.5f;
            const float dx = px - cx;
            const float dy = py - cy;
            local_sum += 0.2f * sqrtf(dx * dx + dy * dy);
            local_cnt += 1u;
        }
    }

    // weight>0 count: separate coalesced grid-stride pass over n
    for (int i = gid; i < n; i += stride) {
        local_wpos += (weight[i] > 0.0f) ? 1u : 0u;
    }

    // ---- wave (64) reduction ----
    #pragma unroll
    for (int off = 32; off > 0; off >>= 1) {
        local_sum  += __shfl_down(local_sum, off, 64);
        local_cnt  += __shfl_down(local_cnt, off, 64);
        local_wpos += __shfl_down(local_wpos, off, 64);
    }

    // ---- block reduction across 4 waves ----
    __shared__ float        s_sum[4];
    __shared__ unsigned int s_cnt[4];
    __shared__ unsigned int s_wpos[4];
    const int lane = threadIdx.x & 63;
    const int wave = threadIdx.x >> 6;
    if (lane == 0) { s_sum[wave] = local_sum; s_cnt[wave] = local_cnt; s_wpos[wave] = local_wpos; }
    __syncthreads();
    if (threadIdx.x == 0) {
        double bsum = 0.0;
        unsigned int bcnt = 0u, bwpos = 0u;
        #pragma unroll
        for (int i = 0; i < 4; ++i) { bsum += (double)s_sum[i]; bcnt += s_cnt[i]; bwpos += s_wpos[i]; }
        part_sum[blockIdx.x]  = bsum;     // own slot: no init, no atomics
        part_cnt[blockIdx.x]  = bcnt;
        part_wpos[blockIdx.x] = bwpos;
    }
}

__global__ void __launch_bounds__(64) sbl_finalize(
    const double* __restrict__ part_sum,
    const unsigned int* __restrict__ part_cnt,
    const unsigned int* __restrict__ part_wpos,
    float* __restrict__ out,
    int nblocks)
{
    const int lane = threadIdx.x;   // single 64-lane wave
    double s = 0.0;
    unsigned int c = 0u, w = 0u;
    for (int i = lane; i < nblocks; i += 64) {
        s += part_sum[i];
        c += part_cnt[i];
        w += part_wpos[i];
    }
    #pragma unroll
    for (int off = 32; off > 0; off >>= 1) {
        s += __shfl_down(s, off, 64);
        c += __shfl_down(c, off, 64);
        w += __shfl_down(w, off, 64);
    }
    if (lane == 0) {
        double loss_sb = (c > 0u) ? (s / (double)c) : 0.0;
        double avg_factor = (double)w + 1e-6;
        out[0] = (float)(loss_sb / avg_factor);
    }
}

extern "C" void kernel_launch(void* const* d_in, const int* in_sizes, int n_in,
                              void* d_out, int out_size, void* d_ws, size_t ws_size,
                              hipStream_t stream) {
    const float* pts    = (const float*)d_in[0];   // [n,18]
    const float* quads  = (const float*)d_in[1];   // [n,8]
    const float* weight = (const float*)d_in[2];   // [n]
    float* out = (float*)d_out;

    const int n = in_sizes[2];

    double*       part_sum  = (double*)d_ws;
    unsigned int* part_cnt  = (unsigned int*)((char*)d_ws + SBL_NBLOCKS * sizeof(double));
    unsigned int* part_wpos = (unsigned int*)((char*)d_ws + SBL_NBLOCKS * (sizeof(double) + sizeof(unsigned int)));

    sbl_main<<<SBL_NBLOCKS, SBL_BLOCK, 0, stream>>>(pts, quads, weight,
                                                    part_sum, part_cnt, part_wpos, n);
    sbl_finalize<<<1, 64, 0, stream>>>(part_sum, part_cnt, part_wpos, out, SBL_NBLOCKS);
}

// Round 3
// 138.512 us; speedup vs baseline: 1.7811x; 1.0291x over previous
//
#include <hip/hip_runtime.h>

// SpatialBorderLoss — per-point parallel, unroll-by-4 for memory-level parallelism.
//
// R2 post-mortem: coalesced per-point kernel ran ~40us vs 17us traffic floor with
// no pipe saturated -> latency-bound (3 loads/iter, waitcnt gates compute, no SW
// pipelining across grid-stride iters). Fix: manual 4x unroll -> 12 independent
// loads in flight per wave before any compute. Finalize widened to 256 threads.
//
// ws layout: double part_sum[2048] @ 0       (16 KB)
//            uint   part_cnt[2048] @ 16384   ( 8 KB)
//            uint   part_wpos[2048]@ 24576   ( 8 KB)

#define SBL_NBLOCKS 2048
#define SBL_BLOCK   256

__device__ __forceinline__ void sbl_point(float px, float py,
                                          const float4& qa, const float4& qb,
                                          float& local_sum, unsigned int& local_cnt)
{
    const float vx0 = qa.x, vy0 = qa.y, vx1 = qa.z, vy1 = qa.w;
    const float vx2 = qb.x, vy2 = qb.y, vx3 = qb.z, vy3 = qb.w;

    int crossings = 0;
    // Edge (v_i, v_{i-1}) per jnp.roll(v,1): (0,3),(1,0),(2,1),(3,2).
    // straddle pins sign of d=vyj-vy, so the divide becomes a signed mul-compare.
    #define SBL_EDGE(VX, VY, VXJ, VYJ)                                   \
    do {                                                                 \
        bool str_ = ((VY) > py) != ((VYJ) > py);                         \
        float d   = (VYJ) - (VY);                                        \
        float num = ((VXJ) - (VX)) * (py - (VY));                        \
        float lhs = (px - (VX)) * d;                                     \
        bool cond = (d > 0.0f) ? (lhs < num) : (lhs > num);              \
        crossings += (str_ && cond) ? 1 : 0;                             \
    } while (0)

    SBL_EDGE(vx0, vy0, vx3, vy3);
    SBL_EDGE(vx1, vy1, vx0, vy0);
    SBL_EDGE(vx2, vy2, vx1, vy1);
    SBL_EDGE(vx3, vy3, vx2, vy2);
    #undef SBL_EDGE

    if ((crossings & 1) == 0) {        // outside
        const float cx = (vx0 + vx2) * 0.5f;
        const float cy = (vy0 + vy2) * 0.5f;
        const float dx = px - cx;
        const float dy = py - cy;
        local_sum += 0.2f * sqrtf(dx * dx + dy * dy);
        local_cnt += 1u;
    }
}

__global__ void __launch_bounds__(SBL_BLOCK) sbl_main(
    const float* __restrict__ pts,      // [n,18]
    const float* __restrict__ quads,    // [n,8]
    const float* __restrict__ weight,   // [n]
    double* __restrict__ part_sum,
    unsigned int* __restrict__ part_cnt,
    unsigned int* __restrict__ part_wpos,
    int n)
{
    const int gid    = blockIdx.x * SBL_BLOCK + threadIdx.x;
    const int stride = gridDim.x * SBL_BLOCK;
    const int total  = n * 9;

    const float2* __restrict__ p2 = reinterpret_cast<const float2*>(pts);
    const float4* __restrict__ q4 = reinterpret_cast<const float4*>(quads);

    float local_sum = 0.0f;
    unsigned int local_cnt = 0u;
    unsigned int local_wpos = 0u;

    int i = gid;
    // ---- unrolled by 4: 12 independent loads in flight ----
    for (; i + 3 * stride < total; i += 4 * stride) {
        const int p0 = i, p1 = i + stride, p2i = i + 2 * stride, p3 = i + 3 * stride;
        const int r0 = (int)((unsigned int)p0 / 9u);
        const int r1 = (int)((unsigned int)p1 / 9u);
        const int r2 = (int)((unsigned int)p2i / 9u);
        const int r3 = (int)((unsigned int)p3 / 9u);

        const float2 a0 = p2[p0];
        const float2 a1 = p2[p1];
        const float2 a2 = p2[p2i];
        const float2 a3 = p2[p3];
        const float4 qa0 = q4[(size_t)r0 * 2], qb0 = q4[(size_t)r0 * 2 + 1];
        const float4 qa1 = q4[(size_t)r1 * 2], qb1 = q4[(size_t)r1 * 2 + 1];
        const float4 qa2 = q4[(size_t)r2 * 2], qb2 = q4[(size_t)r2 * 2 + 1];
        const float4 qa3 = q4[(size_t)r3 * 2], qb3 = q4[(size_t)r3 * 2 + 1];

        sbl_point(a0.x, a0.y, qa0, qb0, local_sum, local_cnt);
        sbl_point(a1.x, a1.y, qa1, qb1, local_sum, local_cnt);
        sbl_point(a2.x, a2.y, qa2, qb2, local_sum, local_cnt);
        sbl_point(a3.x, a3.y, qa3, qb3, local_sum, local_cnt);
    }
    // ---- tail ----
    for (; i < total; i += stride) {
        const int row = (int)((unsigned int)i / 9u);
        const float2 a = p2[i];
        const float4 qa = q4[(size_t)row * 2], qb = q4[(size_t)row * 2 + 1];
        sbl_point(a.x, a.y, qa, qb, local_sum, local_cnt);
    }

    // weight>0 count: coalesced grid-stride pass over n (unrolled x4)
    int j = gid;
    for (; j + 3 * stride < n; j += 4 * stride) {
        const float w0 = weight[j];
        const float w1 = weight[j + stride];
        const float w2 = weight[j + 2 * stride];
        const float w3 = weight[j + 3 * stride];
        local_wpos += (w0 > 0.0f) + (w1 > 0.0f) + (w2 > 0.0f) + (w3 > 0.0f);
    }
    for (; j < n; j += stride) {
        local_wpos += (weight[j] > 0.0f) ? 1u : 0u;
    }

    // ---- wave (64) reduction ----
    #pragma unroll
    for (int off = 32; off > 0; off >>= 1) {
        local_sum  += __shfl_down(local_sum, off, 64);
        local_cnt  += __shfl_down(local_cnt, off, 64);
        local_wpos += __shfl_down(local_wpos, off, 64);
    }

    // ---- block reduction across 4 waves ----
    __shared__ float        s_sum[4];
    __shared__ unsigned int s_cnt[4];
    __shared__ unsigned int s_wpos[4];
    const int lane = threadIdx.x & 63;
    const int wave = threadIdx.x >> 6;
    if (lane == 0) { s_sum[wave] = local_sum; s_cnt[wave] = local_cnt; s_wpos[wave] = local_wpos; }
    __syncthreads();
    if (threadIdx.x == 0) {
        double bsum = 0.0;
        unsigned int bcnt = 0u, bwpos = 0u;
        #pragma unroll
        for (int k = 0; k < 4; ++k) { bsum += (double)s_sum[k]; bcnt += s_cnt[k]; bwpos += s_wpos[k]; }
        part_sum[blockIdx.x]  = bsum;     // own slot: no init, no atomics
        part_cnt[blockIdx.x]  = bcnt;
        part_wpos[blockIdx.x] = bwpos;
    }
}

__global__ void __launch_bounds__(256) sbl_finalize(
    const double* __restrict__ part_sum,
    const unsigned int* __restrict__ part_cnt,
    const unsigned int* __restrict__ part_wpos,
    float* __restrict__ out,
    int nblocks)
{
    const int tid = threadIdx.x;      // 256 threads = 4 waves
    double s = 0.0;
    unsigned int c = 0u, w = 0u;
    for (int i = tid; i < nblocks; i += 256) {   // 8 iterations, independent
        s += part_sum[i];
        c += part_cnt[i];
        w += part_wpos[i];
    }
    #pragma unroll
    for (int off = 32; off > 0; off >>= 1) {
        s += __shfl_down(s, off, 64);
        c += __shfl_down(c, off, 64);
        w += __shfl_down(w, off, 64);
    }
    __shared__ double       fs[4];
    __shared__ unsigned int fc[4], fw[4];
    const int lane = tid & 63, wave = tid >> 6;
    if (lane == 0) { fs[wave] = s; fc[wave] = c; fw[wave] = w; }
    __syncthreads();
    if (tid == 0) {
        double ts = 0.0; unsigned int tc = 0u, tw = 0u;
        #pragma unroll
        for (int k = 0; k < 4; ++k) { ts += fs[k]; tc += fc[k]; tw += fw[k]; }
        double loss_sb = (tc > 0u) ? (ts / (double)tc) : 0.0;
        double avg_factor = (double)tw + 1e-6;
        out[0] = (float)(loss_sb / avg_factor);
    }
}

extern "C" void kernel_launch(void* const* d_in, const int* in_sizes, int n_in,
                              void* d_out, int out_size, void* d_ws, size_t ws_size,
                              hipStream_t stream) {
    const float* pts    = (const float*)d_in[0];   // [n,18]
    const float* quads  = (const float*)d_in[1];   // [n,8]
    const float* weight = (const float*)d_in[2];   // [n]
    float* out = (float*)d_out;

    const int n = in_sizes[2];

    double*       part_sum  = (double*)d_ws;
    unsigned int* part_cnt  = (unsigned int*)((char*)d_ws + SBL_NBLOCKS * sizeof(double));
    unsigned int* part_wpos = (unsigned int*)((char*)d_ws + SBL_NBLOCKS * (sizeof(double) + sizeof(unsigned int)));

    sbl_main<<<SBL_NBLOCKS, SBL_BLOCK, 0, stream>>>(pts, quads, weight,
                                                    part_sum, part_cnt, part_wpos, n);
    sbl_finalize<<<1, 256, 0, stream>>>(part_sum, part_cnt, part_wpos, out, SBL_NBLOCKS);
}